// Round 4
// baseline (578.133 us; speedup 1.0000x reference)
//
#include <hip/hip_runtime.h>

// GCN forward, MI355X. v4 — logic identical to v2/v3; resubmitted after three
// transport-level container failures (kernel has never executed on hardware).

#define N_NODES 50000
#define N_EDGES 800000
#define D 128

// ---------------- CSR build ----------------

__global__ __launch_bounds__(256) void k_count(const int* __restrict__ src, const int* __restrict__ dst,
                                               int* __restrict__ degcnt, int* __restrict__ rowcnt, int ne) {
    int e = blockIdx.x * 256 + threadIdx.x;
    if (e < ne) {
        atomicAdd(&degcnt[src[e]], 1);   // out-degree (norm='left')
        atomicAdd(&rowcnt[dst[e]], 1);   // in-degree histogram for CSR-by-dst
    }
}

__global__ __launch_bounds__(256) void k_deginv(const int* __restrict__ degcnt, float* __restrict__ dinv, int n) {
    int i = blockIdx.x * 256 + threadIdx.x;
    if (i < n) {
        int d = degcnt[i];
        dinv[i] = 1.0f / (float)(d > 1 ? d : 1);
    }
}

__global__ __launch_bounds__(1024) void k_scan1(const int* __restrict__ cnt, int* __restrict__ excl,
                                                int* __restrict__ blocksum, int n) {
    __shared__ int wsum[16];
    int i = blockIdx.x * 1024 + threadIdx.x;
    int v = (i < n) ? cnt[i] : 0;
    int lane = threadIdx.x & 63, wid = threadIdx.x >> 6;
    int x = v;
#pragma unroll
    for (int off = 1; off < 64; off <<= 1) {
        int y = __shfl_up(x, off, 64);
        if (lane >= off) x += y;
    }
    if (lane == 63) wsum[wid] = x;
    __syncthreads();
    if (threadIdx.x == 0) {
        int run = 0;
        for (int w = 0; w < 16; w++) { int t = wsum[w]; wsum[w] = run; run += t; }
        blocksum[blockIdx.x] = run;
    }
    __syncthreads();
    if (i < n) excl[i] = (x - v) + wsum[wid];
}

__global__ void k_scan2(const int* __restrict__ blocksum, int* __restrict__ blockoff,
                        int* __restrict__ rowptr_last, int nblk) {
    if (threadIdx.x == 0) {
        int run = 0;
        for (int b = 0; b < nblk; b++) { int t = blocksum[b]; blockoff[b] = run; run += t; }
        rowptr_last[0] = run;
    }
}

__global__ __launch_bounds__(1024) void k_scan3(int* __restrict__ excl, const int* __restrict__ blockoff, int n) {
    int i = blockIdx.x * 1024 + threadIdx.x;
    if (i < n) excl[i] += blockoff[blockIdx.x];
}

__global__ __launch_bounds__(256) void k_fill(const int* __restrict__ src, const int* __restrict__ dst,
                                              const int* __restrict__ rowptr, int* __restrict__ fillcnt,
                                              int* __restrict__ csrc, int ne) {
    int e = blockIdx.x * 256 + threadIdx.x;
    if (e < ne) {
        int d = dst[e];
        int pos = atomicAdd(&fillcnt[d], 1);
        csrc[rowptr[d] + pos] = src[e];
    }
}

// ---------------- SpMM aggregation: one wave per dst node ----------------

__global__ __launch_bounds__(64) void k_agg(const float* __restrict__ h, const float* __restrict__ dinv,
                                            const int* __restrict__ rp, const int* __restrict__ csrc,
                                            float* __restrict__ out) {
    int node = blockIdx.x;
    int lane = threadIdx.x;
    int s0 = rp[node], s1 = rp[node + 1];
    __shared__ int  slds[64];
    __shared__ float wl[64];
    float ax = 0.f, ay = 0.f;
    for (int base = s0; base < s1; base += 64) {
        int nn = s1 - base; if (nn > 64) nn = 64;
        if (lane < nn) { int s = csrc[base + lane]; slds[lane] = s; wl[lane] = dinv[s]; }
        __syncthreads();
        for (int j = 0; j < nn; j++) {
            int s = slds[j]; float w = wl[j];
            const float2 hv = *reinterpret_cast<const float2*>(&h[(size_t)s * D + 2 * lane]);
            ax += hv.x * w; ay += hv.y * w;
        }
        __syncthreads();
    }
    float2 r; r.x = ax; r.y = ay;
    *reinterpret_cast<float2*>(&out[(size_t)node * D + 2 * lane]) = r;
}

// ---------------- dense layer: out = act(in @ W + b), in-place safe ----------------

__global__ __launch_bounds__(256) void k_gemm(const float* __restrict__ in, const float* __restrict__ W,
                                              const float* __restrict__ bias, float* __restrict__ out,
                                              int nrows, int relu) {
    __shared__ float wl[D * D];     // 64 KB
    __shared__ float al[4][D];      // 2 KB
    for (int i = threadIdx.x; i < D * D / 4; i += 256)
        reinterpret_cast<float4*>(wl)[i] = reinterpret_cast<const float4*>(W)[i];
    int r = threadIdx.x >> 6, l = threadIdx.x & 63;
    float2 b2 = reinterpret_cast<const float2*>(bias)[l];
    __syncthreads();
    for (int row0 = blockIdx.x * 4; row0 < nrows; row0 += gridDim.x * 4) {
        reinterpret_cast<float2*>(&al[0][0])[threadIdx.x] =
            reinterpret_cast<const float2*>(&in[(size_t)row0 * D])[threadIdx.x];
        __syncthreads();
        float a0 = 0.f, a1 = 0.f;
#pragma unroll 8
        for (int k = 0; k < D; k++) {
            float a = al[r][k];
            float2 w = reinterpret_cast<const float2*>(&wl[k * D])[l];
            a0 += a * w.x; a1 += a * w.y;
        }
        a0 += b2.x; a1 += b2.y;
        if (relu) { a0 = fmaxf(a0, 0.f); a1 = fmaxf(a1, 0.f); }
        float2 o; o.x = a0; o.y = a1;
        reinterpret_cast<float2*>(&out[(size_t)(row0 + r) * D])[l] = o;
        __syncthreads();
    }
}

// ---------------- heads ----------------

__global__ __launch_bounds__(64) void k_pi(const float* __restrict__ h, const float* __restrict__ pw,
                                           const float* __restrict__ pb, float* __restrict__ out,
                                           float* __restrict__ colsum, int nrows) {
    int lane = threadIdx.x;
    float2 p = reinterpret_cast<const float2*>(pw)[lane];
    float pbias = pb[0];
    float csx = 0.f, csy = 0.f;
    for (int n = blockIdx.x; n < nrows; n += gridDim.x) {
        float2 hv = reinterpret_cast<const float2*>(&h[(size_t)n * D])[lane];
        csx += hv.x; csy += hv.y;
        float d = hv.x * p.x + hv.y * p.y;
#pragma unroll
        for (int off = 32; off > 0; off >>= 1) d += __shfl_xor(d, off, 64);
        if (lane == 0) out[n] = d + pbias;
    }
    atomicAdd(&colsum[2 * lane],     csx);
    atomicAdd(&colsum[2 * lane + 1], csy);
}

__global__ __launch_bounds__(128) void k_value(const float* __restrict__ colsum, const float* __restrict__ vw,
                                               const float* __restrict__ vb, float* __restrict__ out) {
    __shared__ float red[128];
    int t = threadIdx.x;
    red[t] = (colsum[t] * (1.0f / (float)N_NODES)) * vw[t];
    __syncthreads();
    for (int s = 64; s > 0; s >>= 1) {
        if (t < s) red[t] += red[t + s];
        __syncthreads();
    }
    if (t == 0) out[0] = red[0] + vb[0];
}

__global__ __launch_bounds__(64) void k_ws_too_small(float* __restrict__ out, int n) {
    int i = blockIdx.x * 64 + threadIdx.x;
    if (i < n) out[i] = -1e30f;   // clean, deterministic validation failure (no OOB writes)
}

// ---------------- launch ----------------

extern "C" void kernel_launch(void* const* d_in, const int* in_sizes, int n_in,
                              void* d_out, int out_size, void* d_ws, size_t ws_size,
                              hipStream_t stream) {
    const float* features = (const float*)d_in[0];
    const int*   src      = (const int*)d_in[1];
    const int*   dst      = (const int*)d_in[2];
    const float* W1 = (const float*)d_in[3];
    const float* b1 = (const float*)d_in[4];
    const float* W2 = (const float*)d_in[5];
    const float* b2 = (const float*)d_in[6];
    const float* W3 = (const float*)d_in[7];
    const float* b3 = (const float*)d_in[8];
    const float* pw = (const float*)d_in[9];
    const float* pb = (const float*)d_in[10];
    const float* vw = (const float*)d_in[11];
    const float* vb = (const float*)d_in[12];
    float* out = (float*)d_out;

    char* ws = (char*)d_ws;
    size_t off = 0;
    auto alloc = [&](size_t bytes) -> char* {
        char* p = ws + off;
        off += (bytes + 255) & ~(size_t)255;
        return p;
    };
    int*   degcnt   = (int*)alloc((size_t)N_NODES * 4);
    int*   rowcnt   = (int*)alloc((size_t)N_NODES * 4);
    int*   fillcnt  = (int*)alloc((size_t)N_NODES * 4);
    float* dinv     = (float*)alloc((size_t)N_NODES * 4);
    int*   rowptr   = (int*)alloc((size_t)(N_NODES + 1) * 4);
    int*   blocksum = (int*)alloc(64 * 4);
    int*   blockoff = (int*)alloc(64 * 4);
    float* colsum   = (float*)alloc(D * 4);
    int*   csrc     = (int*)alloc((size_t)N_EDGES * 4);
    float* bufA     = (float*)alloc((size_t)N_NODES * D * 4);
    float* bufB     = (float*)alloc((size_t)N_NODES * D * 4);

    // Guard: never write past the provided workspace (an OOB write can wedge
    // the GPU / kill the container). If ws is too small, fail validation cleanly.
    if (off > ws_size) {
        k_ws_too_small<<<(out_size + 63) / 64, 64, 0, stream>>>(out, out_size);
        return;
    }

    hipMemsetAsync(degcnt,  0, (size_t)N_NODES * 4, stream);
    hipMemsetAsync(rowcnt,  0, (size_t)N_NODES * 4, stream);
    hipMemsetAsync(fillcnt, 0, (size_t)N_NODES * 4, stream);
    hipMemsetAsync(colsum,  0, (size_t)D * 4, stream);

    int eblocks = (N_EDGES + 255) / 256;
    k_count<<<eblocks, 256, 0, stream>>>(src, dst, degcnt, rowcnt, N_EDGES);
    k_deginv<<<(N_NODES + 255) / 256, 256, 0, stream>>>(degcnt, dinv, N_NODES);

    int nblk = (N_NODES + 1023) / 1024;
    k_scan1<<<nblk, 1024, 0, stream>>>(rowcnt, rowptr, blocksum, N_NODES);
    k_scan2<<<1, 64, 0, stream>>>(blocksum, blockoff, rowptr + N_NODES, nblk);
    k_scan3<<<nblk, 1024, 0, stream>>>(rowptr, blockoff, N_NODES);
    k_fill<<<eblocks, 256, 0, stream>>>(src, dst, rowptr, fillcnt, csrc, N_EDGES);

    // layer 1: features -> bufA (agg), bufA -> bufA (dense + relu)
    k_agg<<<N_NODES, 64, 0, stream>>>(features, dinv, rowptr, csrc, bufA);
    k_gemm<<<512, 256, 0, stream>>>(bufA, W1, b1, bufA, N_NODES, 1);
    // layer 2
    k_agg<<<N_NODES, 64, 0, stream>>>(bufA, dinv, rowptr, csrc, bufB);
    k_gemm<<<512, 256, 0, stream>>>(bufB, W2, b2, bufB, N_NODES, 1);
    // layer 3 (no relu)
    k_agg<<<N_NODES, 64, 0, stream>>>(bufB, dinv, rowptr, csrc, bufA);
    k_gemm<<<512, 256, 0, stream>>>(bufA, W3, b3, bufA, N_NODES, 0);

    // heads
    k_pi<<<512, 64, 0, stream>>>(bufA, pw, pb, out, colsum, N_NODES);
    k_value<<<1, 128, 0, stream>>>(colsum, vw, vb, out + N_NODES);
}

// Round 5
// 464.596 us; speedup vs baseline: 1.2444x; 1.2444x over previous
//
#include <hip/hip_runtime.h>

// GCN forward, MI355X. v5 — register-tiled fp32 GEMM (4x4 per thread, k-major
// A-tile in LDS, b128 LDS reads). Rest identical to v4 (which passed @578us).

#define N_NODES 50000
#define N_EDGES 800000
#define D 128

// ---------------- CSR build ----------------

__global__ __launch_bounds__(256) void k_count(const int* __restrict__ src, const int* __restrict__ dst,
                                               int* __restrict__ degcnt, int* __restrict__ rowcnt, int ne) {
    int e = blockIdx.x * 256 + threadIdx.x;
    if (e < ne) {
        atomicAdd(&degcnt[src[e]], 1);   // out-degree (norm='left')
        atomicAdd(&rowcnt[dst[e]], 1);   // in-degree histogram for CSR-by-dst
    }
}

__global__ __launch_bounds__(256) void k_deginv(const int* __restrict__ degcnt, float* __restrict__ dinv, int n) {
    int i = blockIdx.x * 256 + threadIdx.x;
    if (i < n) {
        int d = degcnt[i];
        dinv[i] = 1.0f / (float)(d > 1 ? d : 1);
    }
}

__global__ __launch_bounds__(1024) void k_scan1(const int* __restrict__ cnt, int* __restrict__ excl,
                                                int* __restrict__ blocksum, int n) {
    __shared__ int wsum[16];
    int i = blockIdx.x * 1024 + threadIdx.x;
    int v = (i < n) ? cnt[i] : 0;
    int lane = threadIdx.x & 63, wid = threadIdx.x >> 6;
    int x = v;
#pragma unroll
    for (int off = 1; off < 64; off <<= 1) {
        int y = __shfl_up(x, off, 64);
        if (lane >= off) x += y;
    }
    if (lane == 63) wsum[wid] = x;
    __syncthreads();
    if (threadIdx.x == 0) {
        int run = 0;
        for (int w = 0; w < 16; w++) { int t = wsum[w]; wsum[w] = run; run += t; }
        blocksum[blockIdx.x] = run;
    }
    __syncthreads();
    if (i < n) excl[i] = (x - v) + wsum[wid];
}

__global__ void k_scan2(const int* __restrict__ blocksum, int* __restrict__ blockoff,
                        int* __restrict__ rowptr_last, int nblk) {
    if (threadIdx.x == 0) {
        int run = 0;
        for (int b = 0; b < nblk; b++) { int t = blocksum[b]; blockoff[b] = run; run += t; }
        rowptr_last[0] = run;
    }
}

__global__ __launch_bounds__(1024) void k_scan3(int* __restrict__ excl, const int* __restrict__ blockoff, int n) {
    int i = blockIdx.x * 1024 + threadIdx.x;
    if (i < n) excl[i] += blockoff[blockIdx.x];
}

__global__ __launch_bounds__(256) void k_fill(const int* __restrict__ src, const int* __restrict__ dst,
                                              const int* __restrict__ rowptr, int* __restrict__ fillcnt,
                                              int* __restrict__ csrc, int ne) {
    int e = blockIdx.x * 256 + threadIdx.x;
    if (e < ne) {
        int d = dst[e];
        int pos = atomicAdd(&fillcnt[d], 1);
        csrc[rowptr[d] + pos] = src[e];
    }
}

// ---------------- SpMM aggregation: one wave per dst node ----------------

__global__ __launch_bounds__(64) void k_agg(const float* __restrict__ h, const float* __restrict__ dinv,
                                            const int* __restrict__ rp, const int* __restrict__ csrc,
                                            float* __restrict__ out) {
    int node = blockIdx.x;
    int lane = threadIdx.x;
    int s0 = rp[node], s1 = rp[node + 1];
    __shared__ int  slds[64];
    __shared__ float wl[64];
    float ax = 0.f, ay = 0.f;
    for (int base = s0; base < s1; base += 64) {
        int nn = s1 - base; if (nn > 64) nn = 64;
        if (lane < nn) { int s = csrc[base + lane]; slds[lane] = s; wl[lane] = dinv[s]; }
        __syncthreads();
        for (int j = 0; j < nn; j++) {
            int s = slds[j]; float w = wl[j];
            const float2 hv = *reinterpret_cast<const float2*>(&h[(size_t)s * D + 2 * lane]);
            ax += hv.x * w; ay += hv.y * w;
        }
        __syncthreads();
    }
    float2 r; r.x = ax; r.y = ay;
    *reinterpret_cast<float2*>(&out[(size_t)node * D + 2 * lane]) = r;
}

// ---------------- dense layer: out = act(in @ W + b) ----------------
// 256 threads; tile = 32 rows x 128 cols; each thread: 4 rows x 4 cols.
// LDS: W row-major [k][n] 64KB + A^T k-major [k][row] 16KB = 80KB -> 2 blocks/CU.
// Per k per thread: 1 b128 W read (contiguous+broadcast) + 1 b128 A read
// (broadcast) + 16 FMAs -> VALU-bound. In-place safe (tile staged pre-store).

__global__ __launch_bounds__(256) void k_gemm(const float* __restrict__ in, const float* __restrict__ W,
                                              const float* __restrict__ bias, float* __restrict__ out,
                                              int nrows, int relu) {
    __shared__ float wl[D * D];      // 64 KB: wl[k*128 + n]
    __shared__ float at[D * 32];     // 16 KB: at[k*32 + row], bank = row&31 -> conflict-free
    int t = threadIdx.x;
    for (int i = t; i < D * D / 4; i += 256)
        reinterpret_cast<float4*>(wl)[i] = reinterpret_cast<const float4*>(W)[i];
    const int tx = t & 31;          // col group: cols tx*4 .. tx*4+3
    const int ty = t >> 5;          // row group: rows ty*4 .. ty*4+3
    const int ldrow = t & 31;       // staging: row within tile
    const int ldc   = t >> 5;       // staging: k-chunk (16 k's)
    float4 bv = reinterpret_cast<const float4*>(bias)[tx];
    int ntiles = (nrows + 31) / 32;

    for (int tile = blockIdx.x; tile < ntiles; tile += gridDim.x) {
        int row0 = tile * 32;
        __syncthreads();            // prior-iter readers done before restaging
        {
            int gr = row0 + ldrow;
            float va[16];
            if (gr < nrows) {
                const float4* ap = reinterpret_cast<const float4*>(&in[(size_t)gr * D + ldc * 16]);
#pragma unroll
                for (int q = 0; q < 4; q++) {
                    float4 v = ap[q];
                    va[q * 4 + 0] = v.x; va[q * 4 + 1] = v.y;
                    va[q * 4 + 2] = v.z; va[q * 4 + 3] = v.w;
                }
            } else {
#pragma unroll
                for (int q = 0; q < 16; q++) va[q] = 0.f;
            }
            int kb = ldc * 16;
#pragma unroll
            for (int j = 0; j < 16; j++) at[(kb + j) * 32 + ldrow] = va[j];
        }
        __syncthreads();

        float acc[4][4];
#pragma unroll
        for (int j = 0; j < 4; j++)
#pragma unroll
            for (int c = 0; c < 4; c++) acc[j][c] = 0.f;

#pragma unroll 8
        for (int k = 0; k < D; k++) {
            float4 a = *reinterpret_cast<const float4*>(&at[k * 32 + ty * 4]);
            float4 w = *reinterpret_cast<const float4*>(&wl[k * D + tx * 4]);
            acc[0][0] += a.x * w.x; acc[0][1] += a.x * w.y; acc[0][2] += a.x * w.z; acc[0][3] += a.x * w.w;
            acc[1][0] += a.y * w.x; acc[1][1] += a.y * w.y; acc[1][2] += a.y * w.z; acc[1][3] += a.y * w.w;
            acc[2][0] += a.z * w.x; acc[2][1] += a.z * w.y; acc[2][2] += a.z * w.z; acc[2][3] += a.z * w.w;
            acc[3][0] += a.w * w.x; acc[3][1] += a.w * w.y; acc[3][2] += a.w * w.z; acc[3][3] += a.w * w.w;
        }

#pragma unroll
        for (int j = 0; j < 4; j++) {
            int gr = row0 + ty * 4 + j;
            if (gr < nrows) {
                float4 o;
                o.x = acc[j][0] + bv.x; o.y = acc[j][1] + bv.y;
                o.z = acc[j][2] + bv.z; o.w = acc[j][3] + bv.w;
                if (relu) {
                    o.x = fmaxf(o.x, 0.f); o.y = fmaxf(o.y, 0.f);
                    o.z = fmaxf(o.z, 0.f); o.w = fmaxf(o.w, 0.f);
                }
                reinterpret_cast<float4*>(&out[(size_t)gr * D])[tx] = o;
            }
        }
    }
}

// ---------------- heads ----------------

__global__ __launch_bounds__(64) void k_pi(const float* __restrict__ h, const float* __restrict__ pw,
                                           const float* __restrict__ pb, float* __restrict__ out,
                                           float* __restrict__ colsum, int nrows) {
    int lane = threadIdx.x;
    float2 p = reinterpret_cast<const float2*>(pw)[lane];
    float pbias = pb[0];
    float csx = 0.f, csy = 0.f;
    for (int n = blockIdx.x; n < nrows; n += gridDim.x) {
        float2 hv = reinterpret_cast<const float2*>(&h[(size_t)n * D])[lane];
        csx += hv.x; csy += hv.y;
        float d = hv.x * p.x + hv.y * p.y;
#pragma unroll
        for (int off = 32; off > 0; off >>= 1) d += __shfl_xor(d, off, 64);
        if (lane == 0) out[n] = d + pbias;
    }
    atomicAdd(&colsum[2 * lane],     csx);
    atomicAdd(&colsum[2 * lane + 1], csy);
}

__global__ __launch_bounds__(128) void k_value(const float* __restrict__ colsum, const float* __restrict__ vw,
                                               const float* __restrict__ vb, float* __restrict__ out) {
    __shared__ float red[128];
    int t = threadIdx.x;
    red[t] = (colsum[t] * (1.0f / (float)N_NODES)) * vw[t];
    __syncthreads();
    for (int s = 64; s > 0; s >>= 1) {
        if (t < s) red[t] += red[t + s];
        __syncthreads();
    }
    if (t == 0) out[0] = red[0] + vb[0];
}

__global__ __launch_bounds__(64) void k_ws_too_small(float* __restrict__ out, int n) {
    int i = blockIdx.x * 64 + threadIdx.x;
    if (i < n) out[i] = -1e30f;   // clean, deterministic validation failure (no OOB writes)
}

// ---------------- launch ----------------

extern "C" void kernel_launch(void* const* d_in, const int* in_sizes, int n_in,
                              void* d_out, int out_size, void* d_ws, size_t ws_size,
                              hipStream_t stream) {
    const float* features = (const float*)d_in[0];
    const int*   src      = (const int*)d_in[1];
    const int*   dst      = (const int*)d_in[2];
    const float* W1 = (const float*)d_in[3];
    const float* b1 = (const float*)d_in[4];
    const float* W2 = (const float*)d_in[5];
    const float* b2 = (const float*)d_in[6];
    const float* W3 = (const float*)d_in[7];
    const float* b3 = (const float*)d_in[8];
    const float* pw = (const float*)d_in[9];
    const float* pb = (const float*)d_in[10];
    const float* vw = (const float*)d_in[11];
    const float* vb = (const float*)d_in[12];
    float* out = (float*)d_out;

    char* ws = (char*)d_ws;
    size_t off = 0;
    auto alloc = [&](size_t bytes) -> char* {
        char* p = ws + off;
        off += (bytes + 255) & ~(size_t)255;
        return p;
    };
    int*   degcnt   = (int*)alloc((size_t)N_NODES * 4);
    int*   rowcnt   = (int*)alloc((size_t)N_NODES * 4);
    int*   fillcnt  = (int*)alloc((size_t)N_NODES * 4);
    float* dinv     = (float*)alloc((size_t)N_NODES * 4);
    int*   rowptr   = (int*)alloc((size_t)(N_NODES + 1) * 4);
    int*   blocksum = (int*)alloc(64 * 4);
    int*   blockoff = (int*)alloc(64 * 4);
    float* colsum   = (float*)alloc(D * 4);
    int*   csrc     = (int*)alloc((size_t)N_EDGES * 4);
    float* bufA     = (float*)alloc((size_t)N_NODES * D * 4);
    float* bufB     = (float*)alloc((size_t)N_NODES * D * 4);

    // Guard: never write past the provided workspace.
    if (off > ws_size) {
        k_ws_too_small<<<(out_size + 63) / 64, 64, 0, stream>>>(out, out_size);
        return;
    }

    hipMemsetAsync(degcnt,  0, (size_t)N_NODES * 4, stream);
    hipMemsetAsync(rowcnt,  0, (size_t)N_NODES * 4, stream);
    hipMemsetAsync(fillcnt, 0, (size_t)N_NODES * 4, stream);
    hipMemsetAsync(colsum,  0, (size_t)D * 4, stream);

    int eblocks = (N_EDGES + 255) / 256;
    k_count<<<eblocks, 256, 0, stream>>>(src, dst, degcnt, rowcnt, N_EDGES);
    k_deginv<<<(N_NODES + 255) / 256, 256, 0, stream>>>(degcnt, dinv, N_NODES);

    int nblk = (N_NODES + 1023) / 1024;
    k_scan1<<<nblk, 1024, 0, stream>>>(rowcnt, rowptr, blocksum, N_NODES);
    k_scan2<<<1, 64, 0, stream>>>(blocksum, blockoff, rowptr + N_NODES, nblk);
    k_scan3<<<nblk, 1024, 0, stream>>>(rowptr, blockoff, N_NODES);
    k_fill<<<eblocks, 256, 0, stream>>>(src, dst, rowptr, fillcnt, csrc, N_EDGES);

    // layer 1: features -> bufA (agg), bufA -> bufA (dense + relu)
    k_agg<<<N_NODES, 64, 0, stream>>>(features, dinv, rowptr, csrc, bufA);
    k_gemm<<<512, 256, 0, stream>>>(bufA, W1, b1, bufA, N_NODES, 1);
    // layer 2
    k_agg<<<N_NODES, 64, 0, stream>>>(bufA, dinv, rowptr, csrc, bufB);
    k_gemm<<<512, 256, 0, stream>>>(bufB, W2, b2, bufB, N_NODES, 1);
    // layer 3 (no relu)
    k_agg<<<N_NODES, 64, 0, stream>>>(bufB, dinv, rowptr, csrc, bufA);
    k_gemm<<<512, 256, 0, stream>>>(bufA, W3, b3, bufA, N_NODES, 0);

    // heads
    k_pi<<<512, 64, 0, stream>>>(bufA, pw, pb, out, colsum, N_NODES);
    k_value<<<1, 128, 0, stream>>>(colsum, vw, vb, out + N_NODES);
}

// Round 6
// 459.940 us; speedup vs baseline: 1.2570x; 1.0101x over previous
//
#include <hip/hip_runtime.h>

// GCN forward, MI355X. v6 — (1) PI/colsum head fused into gemm3 epilogue (h3
// never stored), (2) dinv scaling fused into gemm1/2 epilogues + k_scale for
// layer-1 input, (3) k_agg: 2 nodes/wave, float4 lanes, shfl-broadcast edges.

#define N_NODES 50000
#define N_EDGES 800000
#define D 128

// ---------------- CSR build ----------------

__global__ __launch_bounds__(256) void k_count(const int* __restrict__ src, const int* __restrict__ dst,
                                               int* __restrict__ degcnt, int* __restrict__ rowcnt, int ne) {
    int e = blockIdx.x * 256 + threadIdx.x;
    if (e < ne) {
        atomicAdd(&degcnt[src[e]], 1);   // out-degree (norm='left')
        atomicAdd(&rowcnt[dst[e]], 1);   // in-degree histogram for CSR-by-dst
    }
}

__global__ __launch_bounds__(256) void k_deginv(const int* __restrict__ degcnt, float* __restrict__ dinv, int n) {
    int i = blockIdx.x * 256 + threadIdx.x;
    if (i < n) {
        int d = degcnt[i];
        dinv[i] = 1.0f / (float)(d > 1 ? d : 1);
    }
}

__global__ __launch_bounds__(1024) void k_scan1(const int* __restrict__ cnt, int* __restrict__ excl,
                                                int* __restrict__ blocksum, int n) {
    __shared__ int wsum[16];
    int i = blockIdx.x * 1024 + threadIdx.x;
    int v = (i < n) ? cnt[i] : 0;
    int lane = threadIdx.x & 63, wid = threadIdx.x >> 6;
    int x = v;
#pragma unroll
    for (int off = 1; off < 64; off <<= 1) {
        int y = __shfl_up(x, off, 64);
        if (lane >= off) x += y;
    }
    if (lane == 63) wsum[wid] = x;
    __syncthreads();
    if (threadIdx.x == 0) {
        int run = 0;
        for (int w = 0; w < 16; w++) { int t = wsum[w]; wsum[w] = run; run += t; }
        blocksum[blockIdx.x] = run;
    }
    __syncthreads();
    if (i < n) excl[i] = (x - v) + wsum[wid];
}

__global__ void k_scan2(const int* __restrict__ blocksum, int* __restrict__ blockoff,
                        int* __restrict__ rowptr_last, int nblk) {
    if (threadIdx.x == 0) {
        int run = 0;
        for (int b = 0; b < nblk; b++) { int t = blocksum[b]; blockoff[b] = run; run += t; }
        rowptr_last[0] = run;
    }
}

__global__ __launch_bounds__(1024) void k_scan3(int* __restrict__ excl, const int* __restrict__ blockoff, int n) {
    int i = blockIdx.x * 1024 + threadIdx.x;
    if (i < n) excl[i] += blockoff[blockIdx.x];
}

__global__ __launch_bounds__(256) void k_fill(const int* __restrict__ src, const int* __restrict__ dst,
                                              const int* __restrict__ rowptr, int* __restrict__ fillcnt,
                                              int* __restrict__ csrc, int ne) {
    int e = blockIdx.x * 256 + threadIdx.x;
    if (e < ne) {
        int d = dst[e];
        int pos = atomicAdd(&fillcnt[d], 1);
        csrc[rowptr[d] + pos] = src[e];
    }
}

// ---------------- layer-1 input pre-scale: hn = features * dinv[row] ----------------

__global__ __launch_bounds__(256) void k_scale(const float* __restrict__ in, const float* __restrict__ dinv,
                                               float* __restrict__ out, int n4) {
    int i = blockIdx.x * 256 + threadIdx.x;
    if (i < n4) {
        float w = dinv[i >> 5];          // 32 float4 per 128-wide row
        float4 v = reinterpret_cast<const float4*>(in)[i];
        v.x *= w; v.y *= w; v.z *= w; v.w *= w;
        reinterpret_cast<float4*>(out)[i] = v;
    }
}

// ---------------- SpMM aggregation: 2 nodes per wave, gather-add ----------------
// Input is pre-scaled (hn), so agg is a pure sum over incoming edges.

__global__ __launch_bounds__(64) void k_agg(const float* __restrict__ hn,
                                            const int* __restrict__ rp, const int* __restrict__ csrc,
                                            float* __restrict__ out) {
    int lane = threadIdx.x;
    int l32 = lane & 31;
    int node = blockIdx.x * 2 + (lane >> 5);     // N_NODES even -> always valid
    int s0 = rp[node], s1 = rp[node + 1];
    float ax = 0.f, ay = 0.f, az = 0.f, aw = 0.f;
    for (int base = s0; base < s1; base += 32) {
        int nn = s1 - base; if (nn > 32) nn = 32;
        int sv = (l32 < nn) ? csrc[base + l32] : 0;
        for (int j = 0; j < nn; j++) {
            int s = __shfl(sv, j, 32);
            const float4 hv = *reinterpret_cast<const float4*>(&hn[(size_t)s * D + l32 * 4]);
            ax += hv.x; ay += hv.y; az += hv.z; aw += hv.w;
        }
    }
    float4 r; r.x = ax; r.y = ay; r.z = az; r.w = aw;
    *reinterpret_cast<float4*>(&out[(size_t)node * D + l32 * 4]) = r;
}

// ---------------- dense layer (+ optional fused epilogues) ----------------
// 256 threads; tile = 32 rows x 128 cols; thread = 4x4 outputs.
// dscale != nullptr : write act(in@W+b) * dinv[row]   (produces next agg input)
// pw     != nullptr : head mode — PI[row] = o . pw + pb, colsum += o; NO h store.

__global__ __launch_bounds__(256) void k_gemm(const float* __restrict__ in, const float* __restrict__ W,
                                              const float* __restrict__ bias, float* __restrict__ out,
                                              int nrows, int relu,
                                              const float* __restrict__ dscale,
                                              const float* __restrict__ pw, const float* __restrict__ pb,
                                              float* __restrict__ pi_out, float* __restrict__ colsum) {
    __shared__ float wl[D * D];      // 64 KB: wl[k*128 + n]
    __shared__ float at[D * 32];     // 16 KB: at[k*32 + row]
    __shared__ float csl[D];
    int t = threadIdx.x;
    const int head = (pw != nullptr);
    for (int i = t; i < D * D / 4; i += 256)
        reinterpret_cast<float4*>(wl)[i] = reinterpret_cast<const float4*>(W)[i];
    if (head && t < D) csl[t] = 0.f;
    const int tx = t & 31;
    const int ty = t >> 5;
    const int ldrow = t & 31;
    const int ldc   = t >> 5;
    float4 bv = reinterpret_cast<const float4*>(bias)[tx];
    float4 pwv = head ? reinterpret_cast<const float4*>(pw)[tx] : float4{0.f, 0.f, 0.f, 0.f};
    float pb0 = head ? pb[0] : 0.f;
    float cs0 = 0.f, cs1 = 0.f, cs2 = 0.f, cs3 = 0.f;
    int ntiles = (nrows + 31) / 32;

    for (int tile = blockIdx.x; tile < ntiles; tile += gridDim.x) {
        int row0 = tile * 32;
        __syncthreads();            // prior-iter readers done before restaging
        {
            int gr = row0 + ldrow;
            float va[16];
            if (gr < nrows) {
                const float4* ap = reinterpret_cast<const float4*>(&in[(size_t)gr * D + ldc * 16]);
#pragma unroll
                for (int q = 0; q < 4; q++) {
                    float4 v = ap[q];
                    va[q * 4 + 0] = v.x; va[q * 4 + 1] = v.y;
                    va[q * 4 + 2] = v.z; va[q * 4 + 3] = v.w;
                }
            } else {
#pragma unroll
                for (int q = 0; q < 16; q++) va[q] = 0.f;
            }
            int kb = ldc * 16;
#pragma unroll
            for (int j = 0; j < 16; j++) at[(kb + j) * 32 + ldrow] = va[j];
        }
        __syncthreads();

        float acc[4][4];
#pragma unroll
        for (int j = 0; j < 4; j++)
#pragma unroll
            for (int c = 0; c < 4; c++) acc[j][c] = 0.f;

#pragma unroll 8
        for (int k = 0; k < D; k++) {
            float4 a = *reinterpret_cast<const float4*>(&at[k * 32 + ty * 4]);
            float4 w = *reinterpret_cast<const float4*>(&wl[k * D + tx * 4]);
            acc[0][0] += a.x * w.x; acc[0][1] += a.x * w.y; acc[0][2] += a.x * w.z; acc[0][3] += a.x * w.w;
            acc[1][0] += a.y * w.x; acc[1][1] += a.y * w.y; acc[1][2] += a.y * w.z; acc[1][3] += a.y * w.w;
            acc[2][0] += a.z * w.x; acc[2][1] += a.z * w.y; acc[2][2] += a.z * w.z; acc[2][3] += a.z * w.w;
            acc[3][0] += a.w * w.x; acc[3][1] += a.w * w.y; acc[3][2] += a.w * w.z; acc[3][3] += a.w * w.w;
        }

#pragma unroll
        for (int j = 0; j < 4; j++) {
            int gr = row0 + ty * 4 + j;
            if (gr < nrows) {            // uniform across the 32-lane tx group
                float4 o;
                o.x = acc[j][0] + bv.x; o.y = acc[j][1] + bv.y;
                o.z = acc[j][2] + bv.z; o.w = acc[j][3] + bv.w;
                if (relu) {
                    o.x = fmaxf(o.x, 0.f); o.y = fmaxf(o.y, 0.f);
                    o.z = fmaxf(o.z, 0.f); o.w = fmaxf(o.w, 0.f);
                }
                if (head) {
                    cs0 += o.x; cs1 += o.y; cs2 += o.z; cs3 += o.w;
                    float pr = o.x * pwv.x + o.y * pwv.y + o.z * pwv.z + o.w * pwv.w;
#pragma unroll
                    for (int off = 16; off > 0; off >>= 1) pr += __shfl_xor(pr, off, 32);
                    if (tx == 0) pi_out[gr] = pr + pb0;
                } else {
                    if (dscale) {
                        float w = dscale[gr];
                        o.x *= w; o.y *= w; o.z *= w; o.w *= w;
                    }
                    reinterpret_cast<float4*>(&out[(size_t)gr * D])[tx] = o;
                }
            }
        }
    }

    if (head) {
        __syncthreads();
        atomicAdd(&csl[tx * 4 + 0], cs0);
        atomicAdd(&csl[tx * 4 + 1], cs1);
        atomicAdd(&csl[tx * 4 + 2], cs2);
        atomicAdd(&csl[tx * 4 + 3], cs3);
        __syncthreads();
        if (t < D) atomicAdd(&colsum[t], csl[t]);
    }
}

// ---------------- value head ----------------

__global__ __launch_bounds__(128) void k_value(const float* __restrict__ colsum, const float* __restrict__ vw,
                                               const float* __restrict__ vb, float* __restrict__ out) {
    __shared__ float red[128];
    int t = threadIdx.x;
    red[t] = (colsum[t] * (1.0f / (float)N_NODES)) * vw[t];
    __syncthreads();
    for (int s = 64; s > 0; s >>= 1) {
        if (t < s) red[t] += red[t + s];
        __syncthreads();
    }
    if (t == 0) out[0] = red[0] + vb[0];
}

__global__ __launch_bounds__(64) void k_ws_too_small(float* __restrict__ out, int n) {
    int i = blockIdx.x * 64 + threadIdx.x;
    if (i < n) out[i] = -1e30f;
}

// ---------------- launch ----------------

extern "C" void kernel_launch(void* const* d_in, const int* in_sizes, int n_in,
                              void* d_out, int out_size, void* d_ws, size_t ws_size,
                              hipStream_t stream) {
    const float* features = (const float*)d_in[0];
    const int*   src      = (const int*)d_in[1];
    const int*   dst      = (const int*)d_in[2];
    const float* W1 = (const float*)d_in[3];
    const float* b1 = (const float*)d_in[4];
    const float* W2 = (const float*)d_in[5];
    const float* b2 = (const float*)d_in[6];
    const float* W3 = (const float*)d_in[7];
    const float* b3 = (const float*)d_in[8];
    const float* pw = (const float*)d_in[9];
    const float* pb = (const float*)d_in[10];
    const float* vw = (const float*)d_in[11];
    const float* vb = (const float*)d_in[12];
    float* out = (float*)d_out;

    char* ws = (char*)d_ws;
    size_t off = 0;
    auto alloc = [&](size_t bytes) -> char* {
        char* p = ws + off;
        off += (bytes + 255) & ~(size_t)255;
        return p;
    };
    int*   degcnt   = (int*)alloc((size_t)N_NODES * 4);
    int*   rowcnt   = (int*)alloc((size_t)N_NODES * 4);
    int*   fillcnt  = (int*)alloc((size_t)N_NODES * 4);
    float* dinv     = (float*)alloc((size_t)N_NODES * 4);
    int*   rowptr   = (int*)alloc((size_t)(N_NODES + 1) * 4);
    int*   blocksum = (int*)alloc(64 * 4);
    int*   blockoff = (int*)alloc(64 * 4);
    float* colsum   = (float*)alloc(D * 4);
    int*   csrc     = (int*)alloc((size_t)N_EDGES * 4);
    float* bufA     = (float*)alloc((size_t)N_NODES * D * 4);
    float* bufB     = (float*)alloc((size_t)N_NODES * D * 4);

    if (off > ws_size) {
        k_ws_too_small<<<(out_size + 63) / 64, 64, 0, stream>>>(out, out_size);
        return;
    }

    hipMemsetAsync(degcnt,  0, (size_t)N_NODES * 4, stream);
    hipMemsetAsync(rowcnt,  0, (size_t)N_NODES * 4, stream);
    hipMemsetAsync(fillcnt, 0, (size_t)N_NODES * 4, stream);
    hipMemsetAsync(colsum,  0, (size_t)D * 4, stream);

    int eblocks = (N_EDGES + 255) / 256;
    k_count<<<eblocks, 256, 0, stream>>>(src, dst, degcnt, rowcnt, N_EDGES);
    k_deginv<<<(N_NODES + 255) / 256, 256, 0, stream>>>(degcnt, dinv, N_NODES);

    int nblk = (N_NODES + 1023) / 1024;
    k_scan1<<<nblk, 1024, 0, stream>>>(rowcnt, rowptr, blocksum, N_NODES);
    k_scan2<<<1, 64, 0, stream>>>(blocksum, blockoff, rowptr + N_NODES, nblk);
    k_scan3<<<nblk, 1024, 0, stream>>>(rowptr, blockoff, N_NODES);
    k_fill<<<eblocks, 256, 0, stream>>>(src, dst, rowptr, fillcnt, csrc, N_EDGES);

    // hn0 = features * dinv  (layer-1 agg input) -> bufB
    int n4 = N_NODES * D / 4;
    k_scale<<<(n4 + 255) / 256, 256, 0, stream>>>(features, dinv, bufB, n4);

    // layer 1: agg(bufB)->bufA ; gemm: relu + dinv scale -> bufA (= hn1)
    k_agg<<<N_NODES / 2, 64, 0, stream>>>(bufB, rowptr, csrc, bufA);
    k_gemm<<<512, 256, 0, stream>>>(bufA, W1, b1, bufA, N_NODES, 1, dinv,
                                    nullptr, nullptr, nullptr, nullptr);
    // layer 2: agg(bufA)->bufB ; gemm -> bufB (= hn2)
    k_agg<<<N_NODES / 2, 64, 0, stream>>>(bufA, rowptr, csrc, bufB);
    k_gemm<<<512, 256, 0, stream>>>(bufB, W2, b2, bufB, N_NODES, 1, dinv,
                                    nullptr, nullptr, nullptr, nullptr);
    // layer 3: agg(bufB)->bufA ; gemm head mode: PI -> out, colsum; no h store
    k_agg<<<N_NODES / 2, 64, 0, stream>>>(bufB, rowptr, csrc, bufA);
    k_gemm<<<512, 256, 0, stream>>>(bufA, W3, b3, nullptr, N_NODES, 0, nullptr,
                                    pw, pb, out, colsum);

    k_value<<<1, 128, 0, stream>>>(colsum, vw, vb, out + N_NODES);
}

// Round 7
// 401.054 us; speedup vs baseline: 1.4415x; 1.1468x over previous
//
#include <hip/hip_runtime.h>

// GCN forward, MI355X. v7 — (1) 8-way shadow histograms for k_count (atomic
// line contention /8), (2) gemm LDS back to exactly 80KB (2 blocks/CU),
// (3) k_scale removed (layer-1 agg scales on gather), (4) k_agg: 8 nodes per
// 256-thread block, 4-deep pipelined gather loads.

#define N_NODES 50000
#define N_EDGES 800000
#define D 128
#define NSH 8

// ---------------- CSR build ----------------

__global__ __launch_bounds__(256) void k_count(const int* __restrict__ src, const int* __restrict__ dst,
                                               int* __restrict__ deg8, int* __restrict__ row8, int ne) {
    int e = blockIdx.x * 256 + threadIdx.x;
    int sh = (blockIdx.x & (NSH - 1)) * N_NODES;
    if (e < ne) {
        atomicAdd(&deg8[sh + src[e]], 1);   // out-degree (norm='left')
        atomicAdd(&row8[sh + dst[e]], 1);   // in-degree for CSR-by-dst
    }
}

__global__ __launch_bounds__(256) void k_merge(const int* __restrict__ deg8, const int* __restrict__ row8,
                                               float* __restrict__ dinv, int* __restrict__ rowm, int n) {
    int i = blockIdx.x * 256 + threadIdx.x;
    if (i < n) {
        int ds = 0, rs = 0;
#pragma unroll
        for (int k = 0; k < NSH; k++) { ds += deg8[k * N_NODES + i]; rs += row8[k * N_NODES + i]; }
        dinv[i] = 1.0f / (float)(ds > 1 ? ds : 1);
        rowm[i] = rs;
    }
}

__global__ __launch_bounds__(1024) void k_scan1(const int* __restrict__ cnt, int* __restrict__ excl,
                                                int* __restrict__ blocksum, int n) {
    __shared__ int wsum[16];
    int i = blockIdx.x * 1024 + threadIdx.x;
    int v = (i < n) ? cnt[i] : 0;
    int lane = threadIdx.x & 63, wid = threadIdx.x >> 6;
    int x = v;
#pragma unroll
    for (int off = 1; off < 64; off <<= 1) {
        int y = __shfl_up(x, off, 64);
        if (lane >= off) x += y;
    }
    if (lane == 63) wsum[wid] = x;
    __syncthreads();
    if (threadIdx.x == 0) {
        int run = 0;
        for (int w = 0; w < 16; w++) { int t = wsum[w]; wsum[w] = run; run += t; }
        blocksum[blockIdx.x] = run;
    }
    __syncthreads();
    if (i < n) excl[i] = (x - v) + wsum[wid];
}

__global__ void k_scan2(const int* __restrict__ blocksum, int* __restrict__ blockoff,
                        int* __restrict__ rowptr_last, int nblk) {
    if (threadIdx.x == 0) {
        int run = 0;
        for (int b = 0; b < nblk; b++) { int t = blocksum[b]; blockoff[b] = run; run += t; }
        rowptr_last[0] = run;
    }
}

__global__ __launch_bounds__(1024) void k_scan3(int* __restrict__ excl, const int* __restrict__ blockoff, int n) {
    int i = blockIdx.x * 1024 + threadIdx.x;
    if (i < n) excl[i] += blockoff[blockIdx.x];
}

__global__ __launch_bounds__(256) void k_fill(const int* __restrict__ src, const int* __restrict__ dst,
                                              const int* __restrict__ rowptr, int* __restrict__ fillcnt,
                                              int* __restrict__ csrc, int ne) {
    int e = blockIdx.x * 256 + threadIdx.x;
    if (e < ne) {
        int d = dst[e];
        int pos = atomicAdd(&fillcnt[d], 1);
        csrc[rowptr[d] + pos] = src[e];
    }
}

// ---------------- SpMM aggregation: 8 nodes per 256-thread block ----------------
// dinv != nullptr: gather hn[src]*dinv[src] (layer 1). Else pure gather-add.
// Inner loop 4-wide: 4 independent dwordx4 loads in flight per lane.

__global__ __launch_bounds__(256) void k_agg(const float* __restrict__ hn, const float* __restrict__ dinv,
                                             const int* __restrict__ rp, const int* __restrict__ csrc,
                                             float* __restrict__ out) {
    int l32 = threadIdx.x & 31;
    int node = blockIdx.x * 8 + (threadIdx.x >> 5);   // 6250*8 == N_NODES exactly
    int s0 = rp[node], s1 = rp[node + 1];
    const bool scaled = (dinv != nullptr);
    float ax = 0.f, ay = 0.f, az = 0.f, aw = 0.f;
    for (int base = s0; base < s1; base += 32) {
        int nn = s1 - base; if (nn > 32) nn = 32;
        int sv = 0; float dv = 1.f;
        if (l32 < nn) { sv = csrc[base + l32]; if (scaled) dv = dinv[sv]; }
        int j = 0;
        for (; j + 4 <= nn; j += 4) {
            int sa = __shfl(sv, j, 32),     sb = __shfl(sv, j + 1, 32);
            int sc = __shfl(sv, j + 2, 32), sd = __shfl(sv, j + 3, 32);
            float wa = __shfl(dv, j, 32),     wb = __shfl(dv, j + 1, 32);
            float wc = __shfl(dv, j + 2, 32), wd = __shfl(dv, j + 3, 32);
            float4 A = *reinterpret_cast<const float4*>(&hn[(size_t)sa * D + l32 * 4]);
            float4 B = *reinterpret_cast<const float4*>(&hn[(size_t)sb * D + l32 * 4]);
            float4 C = *reinterpret_cast<const float4*>(&hn[(size_t)sc * D + l32 * 4]);
            float4 E = *reinterpret_cast<const float4*>(&hn[(size_t)sd * D + l32 * 4]);
            ax += A.x * wa + B.x * wb + C.x * wc + E.x * wd;
            ay += A.y * wa + B.y * wb + C.y * wc + E.y * wd;
            az += A.z * wa + B.z * wb + C.z * wc + E.z * wd;
            aw += A.w * wa + B.w * wb + C.w * wc + E.w * wd;
        }
        for (; j < nn; j++) {
            int s = __shfl(sv, j, 32);
            float w = __shfl(dv, j, 32);
            float4 A = *reinterpret_cast<const float4*>(&hn[(size_t)s * D + l32 * 4]);
            ax += A.x * w; ay += A.y * w; az += A.z * w; aw += A.w * w;
        }
    }
    float4 r; r.x = ax; r.y = ay; r.z = az; r.w = aw;
    *reinterpret_cast<float4*>(&out[(size_t)node * D + l32 * 4]) = r;
}

// ---------------- dense layer (+ optional fused epilogues) ----------------
// 256 threads; tile = 32 rows x 128 cols; thread = 4x4 outputs. LDS = 80KB
// exactly (2 blocks/CU); head-mode colsum staging reuses at[].
// dscale: write act(in@W+b)*dinv[row]. head (pw): PI+colsum, no h store.

__global__ __launch_bounds__(256) void k_gemm(const float* __restrict__ in, const float* __restrict__ W,
                                              const float* __restrict__ bias, float* __restrict__ out,
                                              int nrows, int relu,
                                              const float* __restrict__ dscale,
                                              const float* __restrict__ pw, const float* __restrict__ pb,
                                              float* __restrict__ pi_out, float* __restrict__ colsum) {
    __shared__ float wl[D * D];      // 64 KB: wl[k*128 + n]
    __shared__ float at[D * 32];     // 16 KB: at[k*32 + row]
    int t = threadIdx.x;
    const int head = (pw != nullptr);
    for (int i = t; i < D * D / 4; i += 256)
        reinterpret_cast<float4*>(wl)[i] = reinterpret_cast<const float4*>(W)[i];
    const int tx = t & 31;
    const int ty = t >> 5;
    const int ldrow = t & 31;
    const int ldc   = t >> 5;
    float4 bv = reinterpret_cast<const float4*>(bias)[tx];
    float4 pwv = head ? reinterpret_cast<const float4*>(pw)[tx] : float4{0.f, 0.f, 0.f, 0.f};
    float pb0 = head ? pb[0] : 0.f;
    float cs0 = 0.f, cs1 = 0.f, cs2 = 0.f, cs3 = 0.f;
    int ntiles = (nrows + 31) / 32;

    for (int tile = blockIdx.x; tile < ntiles; tile += gridDim.x) {
        int row0 = tile * 32;
        __syncthreads();            // prior-iter readers done before restaging
        {
            int gr = row0 + ldrow;
            float va[16];
            if (gr < nrows) {
                const float4* ap = reinterpret_cast<const float4*>(&in[(size_t)gr * D + ldc * 16]);
#pragma unroll
                for (int q = 0; q < 4; q++) {
                    float4 v = ap[q];
                    va[q * 4 + 0] = v.x; va[q * 4 + 1] = v.y;
                    va[q * 4 + 2] = v.z; va[q * 4 + 3] = v.w;
                }
            } else {
#pragma unroll
                for (int q = 0; q < 16; q++) va[q] = 0.f;
            }
            int kb = ldc * 16;
#pragma unroll
            for (int j = 0; j < 16; j++) at[(kb + j) * 32 + ldrow] = va[j];
        }
        __syncthreads();

        float acc[4][4];
#pragma unroll
        for (int j = 0; j < 4; j++)
#pragma unroll
            for (int c = 0; c < 4; c++) acc[j][c] = 0.f;

#pragma unroll 8
        for (int k = 0; k < D; k++) {
            float4 a = *reinterpret_cast<const float4*>(&at[k * 32 + ty * 4]);
            float4 w = *reinterpret_cast<const float4*>(&wl[k * D + tx * 4]);
            acc[0][0] += a.x * w.x; acc[0][1] += a.x * w.y; acc[0][2] += a.x * w.z; acc[0][3] += a.x * w.w;
            acc[1][0] += a.y * w.x; acc[1][1] += a.y * w.y; acc[1][2] += a.y * w.z; acc[1][3] += a.y * w.w;
            acc[2][0] += a.z * w.x; acc[2][1] += a.z * w.y; acc[2][2] += a.z * w.z; acc[2][3] += a.z * w.w;
            acc[3][0] += a.w * w.x; acc[3][1] += a.w * w.y; acc[3][2] += a.w * w.z; acc[3][3] += a.w * w.w;
        }

#pragma unroll
        for (int j = 0; j < 4; j++) {
            int gr = row0 + ty * 4 + j;
            if (gr < nrows) {            // uniform across the 32-lane tx group
                float4 o;
                o.x = acc[j][0] + bv.x; o.y = acc[j][1] + bv.y;
                o.z = acc[j][2] + bv.z; o.w = acc[j][3] + bv.w;
                if (relu) {
                    o.x = fmaxf(o.x, 0.f); o.y = fmaxf(o.y, 0.f);
                    o.z = fmaxf(o.z, 0.f); o.w = fmaxf(o.w, 0.f);
                }
                if (head) {
                    cs0 += o.x; cs1 += o.y; cs2 += o.z; cs3 += o.w;
                    float pr = o.x * pwv.x + o.y * pwv.y + o.z * pwv.z + o.w * pwv.w;
#pragma unroll
                    for (int off = 16; off > 0; off >>= 1) pr += __shfl_xor(pr, off, 32);
                    if (tx == 0) pi_out[gr] = pr + pb0;
                } else {
                    if (dscale) {
                        float w = dscale[gr];
                        o.x *= w; o.y *= w; o.z *= w; o.w *= w;
                    }
                    reinterpret_cast<float4*>(&out[(size_t)gr * D])[tx] = o;
                }
            }
        }
    }

    if (head) {
        __syncthreads();                 // all at[] readers done; reuse as colsum staging
        float* csl = at;
        if (t < D) csl[t] = 0.f;
        __syncthreads();
        atomicAdd(&csl[tx * 4 + 0], cs0);
        atomicAdd(&csl[tx * 4 + 1], cs1);
        atomicAdd(&csl[tx * 4 + 2], cs2);
        atomicAdd(&csl[tx * 4 + 3], cs3);
        __syncthreads();
        if (t < D) atomicAdd(&colsum[t], csl[t]);
    }
}

// ---------------- value head ----------------

__global__ __launch_bounds__(128) void k_value(const float* __restrict__ colsum, const float* __restrict__ vw,
                                               const float* __restrict__ vb, float* __restrict__ out) {
    __shared__ float red[128];
    int t = threadIdx.x;
    red[t] = (colsum[t] * (1.0f / (float)N_NODES)) * vw[t];
    __syncthreads();
    for (int s = 64; s > 0; s >>= 1) {
        if (t < s) red[t] += red[t + s];
        __syncthreads();
    }
    if (t == 0) out[0] = red[0] + vb[0];
}

__global__ __launch_bounds__(64) void k_ws_too_small(float* __restrict__ out, int n) {
    int i = blockIdx.x * 64 + threadIdx.x;
    if (i < n) out[i] = -1e30f;
}

// ---------------- launch ----------------

extern "C" void kernel_launch(void* const* d_in, const int* in_sizes, int n_in,
                              void* d_out, int out_size, void* d_ws, size_t ws_size,
                              hipStream_t stream) {
    const float* features = (const float*)d_in[0];
    const int*   src      = (const int*)d_in[1];
    const int*   dst      = (const int*)d_in[2];
    const float* W1 = (const float*)d_in[3];
    const float* b1 = (const float*)d_in[4];
    const float* W2 = (const float*)d_in[5];
    const float* b2 = (const float*)d_in[6];
    const float* W3 = (const float*)d_in[7];
    const float* b3 = (const float*)d_in[8];
    const float* pw = (const float*)d_in[9];
    const float* pb = (const float*)d_in[10];
    const float* vw = (const float*)d_in[11];
    const float* vb = (const float*)d_in[12];
    float* out = (float*)d_out;

    char* ws = (char*)d_ws;
    size_t off = 0;
    auto alloc = [&](size_t bytes) -> char* {
        char* p = ws + off;
        off += (bytes + 255) & ~(size_t)255;
        return p;
    };
    float* dinv     = (float*)alloc((size_t)N_NODES * 4);
    int*   rowptr   = (int*)alloc((size_t)(N_NODES + 1) * 4);
    int*   blocksum = (int*)alloc(64 * 4);
    int*   blockoff = (int*)alloc(64 * 4);
    float* colsum   = (float*)alloc(D * 4);
    int*   csrc     = (int*)alloc((size_t)N_EDGES * 4);
    float* bufA     = (float*)alloc((size_t)N_NODES * D * 4);
    float* bufB     = (float*)alloc((size_t)N_NODES * D * 4);

    // CSR-build temporaries overlay bufB (dead until agg-2 writes it):
    // [deg8: 8N][row8: 8N][rowm: N][fillcnt: N] ints = 3.6 MB << 25.6 MB.
    int* deg8    = (int*)bufB;
    int* row8    = deg8 + (size_t)NSH * N_NODES;
    int* rowm    = row8 + (size_t)NSH * N_NODES;
    int* fillcnt = rowm + N_NODES;

    if (off > ws_size) {
        k_ws_too_small<<<(out_size + 63) / 64, 64, 0, stream>>>(out, out_size);
        return;
    }

    hipMemsetAsync(deg8,    0, (size_t)NSH * N_NODES * 4, stream);
    hipMemsetAsync(row8,    0, (size_t)NSH * N_NODES * 4, stream);
    hipMemsetAsync(fillcnt, 0, (size_t)N_NODES * 4, stream);
    hipMemsetAsync(colsum,  0, (size_t)D * 4, stream);

    int eblocks = (N_EDGES + 255) / 256;
    k_count<<<eblocks, 256, 0, stream>>>(src, dst, deg8, row8, N_EDGES);
    k_merge<<<(N_NODES + 255) / 256, 256, 0, stream>>>(deg8, row8, dinv, rowm, N_NODES);

    int nblk = (N_NODES + 1023) / 1024;
    k_scan1<<<nblk, 1024, 0, stream>>>(rowm, rowptr, blocksum, N_NODES);
    k_scan2<<<1, 64, 0, stream>>>(blocksum, blockoff, rowptr + N_NODES, nblk);
    k_scan3<<<nblk, 1024, 0, stream>>>(rowptr, blockoff, N_NODES);
    k_fill<<<eblocks, 256, 0, stream>>>(src, dst, rowptr, fillcnt, csrc, N_EDGES);

    // layer 1: agg gathers features*dinv directly -> bufA ; gemm in-place (+dinv scale)
    k_agg<<<N_NODES / 8, 256, 0, stream>>>(features, dinv, rowptr, csrc, bufA);
    k_gemm<<<512, 256, 0, stream>>>(bufA, W1, b1, bufA, N_NODES, 1, dinv,
                                    nullptr, nullptr, nullptr, nullptr);
    // layer 2 (input already scaled by gemm1 epilogue)
    k_agg<<<N_NODES / 8, 256, 0, stream>>>(bufA, nullptr, rowptr, csrc, bufB);
    k_gemm<<<512, 256, 0, stream>>>(bufB, W2, b2, bufB, N_NODES, 1, dinv,
                                    nullptr, nullptr, nullptr, nullptr);
    // layer 3: head mode (PI -> out, colsum; h3 never stored)
    k_agg<<<N_NODES / 8, 256, 0, stream>>>(bufB, nullptr, rowptr, csrc, bufA);
    k_gemm<<<512, 256, 0, stream>>>(bufA, W3, b3, nullptr, N_NODES, 0, nullptr,
                                    pw, pb, out, colsum);

    k_value<<<1, 128, 0, stream>>>(colsum, vw, vb, out + N_NODES);
}